// Round 5
// baseline (446.326 us; speedup 1.0000x reference)
//
#include <hip/hip_runtime.h>
#include <math.h>

#define IN_DIM  8192
#define OUT_DIM 8192
#define BATCH   8192
#define ROWS    32     // batch rows per block
#define T       1024   // threads per block

// Direct global->LDS DMA, 16B per lane. LDS dest must be wave-uniform base
// (HW writes lane i at base + i*16); global src is per-lane.
#define GLOAD_LDS16(g, l) __builtin_amdgcn_global_load_lds( \
    (const __attribute__((address_space(1))) void*)(g),     \
    (__attribute__((address_space(3))) void*)(l), 16, 0, 0)

// GATE_COEFFS columns (g0,g1,g2,g3) per row i
__device__ __constant__ float GC0[16] = {0,0,0,0, 0,0,0,0, 1,1,1,1, 1,1,1,1};
__device__ __constant__ float GC1[16] = {0,0,1,1, 0,0,1,1, -1,-1,0,0, -1,-1,0,0};
__device__ __constant__ float GC2[16] = {0,0,0,0, 1,1,1,1, -1,-1,-1,-1, 0,0,0,0};
__device__ __constant__ float GC3[16] = {0,1,-1,0, -1,0,-2,-1, 1,2,0,1, 0,1,-1,0};

// Kernel 1: c[j] = softmax(weight[j,:]) @ GATE_COEFFS  -> float4 per column
__global__ __launch_bounds__(256) void compute_c_kernel(
    const float* __restrict__ weight, float4* __restrict__ c)
{
    int row = blockIdx.x * 256 + threadIdx.x;
    if (row >= OUT_DIM) return;
    const float* wr = weight + (size_t)row * 16;
    float v[16];
    float m = -1e30f;
#pragma unroll
    for (int i = 0; i < 16; ++i) { v[i] = wr[i]; m = fmaxf(m, v[i]); }
    float s = 0.f;
#pragma unroll
    for (int i = 0; i < 16; ++i) { v[i] = __expf(v[i] - m); s += v[i]; }
    float inv = 1.0f / s;
    float c0 = 0.f, c1 = 0.f, c2 = 0.f, c3 = 0.f;
#pragma unroll
    for (int i = 0; i < 16; ++i) {
        c0 = fmaf(v[i], GC0[i], c0);
        c1 = fmaf(v[i], GC1[i], c1);
        c2 = fmaf(v[i], GC2[i], c2);
        c3 = fmaf(v[i], GC3[i], c3);
    }
    c[row] = make_float4(c0 * inv, c1 * inv, c2 * inv, c3 * inv);
}

// Kernel 2: persistent block over 32 rows, 1 block/CU.
// - idx/c register-resident for block lifetime (~48 VGPR)
// - x row double-buffered in LDS via global_load_lds DMA (no reg round-trip)
// - counted s_waitcnt vmcnt(2) + raw s_barrier per row: waits ONLY the two
//   staging DMAs; output stores drain in background (no vmcnt(0) in loop).
__global__ __launch_bounds__(T, 4) void gate_main_kernel(
    const float* __restrict__ x,
    const float4* __restrict__ c,
    const int4* __restrict__ ia4,
    const int4* __restrict__ ib4,
    float4* __restrict__ out)
{
    __shared__ float buf[2][IN_DIM];          // 64 KB
    const int tid  = threadIdx.x;
    const int wave = tid >> 6;
    const size_t r0 = (size_t)blockIdx.x * ROWS;

    // Register-resident idx/c: thread owns output quads q0, q1 for all rows.
    const int q0 = tid, q1 = tid + T;
    const int4 iaA = ia4[q0], ibA = ib4[q0];
    const int4 iaB = ia4[q1], ibB = ib4[q1];
    const float4 cA0 = c[4*q0+0], cA1 = c[4*q0+1], cA2 = c[4*q0+2], cA3 = c[4*q0+3];
    const float4 cB0 = c[4*q1+0], cB1 = c[4*q1+1], cB2 = c[4*q1+2], cB3 = c[4*q1+3];

    // Prologue: stage row 0 into buf[0].
    {
        const float* src = x + r0 * IN_DIM;
        GLOAD_LDS16(src + (tid << 2),        &buf[0][wave << 8]);
        GLOAD_LDS16(src + 4096 + (tid << 2), &buf[0][4096 + (wave << 8)]);
    }
    asm volatile("s_waitcnt vmcnt(0)" ::: "memory");
    __builtin_amdgcn_s_barrier();

    for (int r = 0; r < ROWS; ++r) {
        const int cur = r & 1;

        // (1) issue next-row DMA into the other buffer (safe: that buffer's
        // readers all drained at the previous barrier).
        if (r + 1 < ROWS) {
            const float* src = x + (r0 + r + 1) * IN_DIM;
            float* bn = buf[cur ^ 1];
            GLOAD_LDS16(src + (tid << 2),        bn + (wave << 8));
            GLOAD_LDS16(src + 4096 + (tid << 2), bn + 4096 + (wave << 8));
        }
        asm volatile("" ::: "memory");   // pin DMA issue before the stores below

        // (2) gather + compute + store current row
        const float* xr = buf[cur];
        float4* orow = out + (r0 + r) * (OUT_DIM / 4);
        {
            float a0 = xr[iaA.x], b0 = xr[ibA.x];
            float a1 = xr[iaA.y], b1 = xr[ibA.y];
            float a2 = xr[iaA.z], b2 = xr[ibA.z];
            float a3 = xr[iaA.w], b3 = xr[ibA.w];
            float4 o;
            o.x = fmaf(a0, fmaf(b0, cA0.w, cA0.y), fmaf(b0, cA0.z, cA0.x));
            o.y = fmaf(a1, fmaf(b1, cA1.w, cA1.y), fmaf(b1, cA1.z, cA1.x));
            o.z = fmaf(a2, fmaf(b2, cA2.w, cA2.y), fmaf(b2, cA2.z, cA2.x));
            o.w = fmaf(a3, fmaf(b3, cA3.w, cA3.y), fmaf(b3, cA3.z, cA3.x));
            orow[q0] = o;
        }
        {
            float a0 = xr[iaB.x], b0 = xr[ibB.x];
            float a1 = xr[iaB.y], b1 = xr[ibB.y];
            float a2 = xr[iaB.z], b2 = xr[ibB.z];
            float a3 = xr[iaB.w], b3 = xr[ibB.w];
            float4 o;
            o.x = fmaf(a0, fmaf(b0, cB0.w, cB0.y), fmaf(b0, cB0.z, cB0.x));
            o.y = fmaf(a1, fmaf(b1, cB1.w, cB1.y), fmaf(b1, cB1.z, cB1.x));
            o.z = fmaf(a2, fmaf(b2, cB2.w, cB2.y), fmaf(b2, cB2.z, cB2.x));
            o.w = fmaf(a3, fmaf(b3, cB3.w, cB3.y), fmaf(b3, cB3.z, cB3.x));
            orow[q1] = o;
        }

        // (3) counted wait: in-order vmem retirement => waiting down to 2
        // outstanding guarantees this row's 2 DMAs landed in LDS; our own 2
        // stores may still be in flight across the barrier (nobody reads them).
        if (r + 1 < ROWS) {
            asm volatile("s_waitcnt vmcnt(2)" ::: "memory");
            __builtin_amdgcn_s_barrier();
        }
    }
}

extern "C" void kernel_launch(void* const* d_in, const int* in_sizes, int n_in,
                              void* d_out, int out_size, void* d_ws, size_t ws_size,
                              hipStream_t stream) {
    const float* x      = (const float*)d_in[0];
    const float* weight = (const float*)d_in[1];
    const int*   idx_a  = (const int*)d_in[2];
    const int*   idx_b  = (const int*)d_in[3];
    float* out = (float*)d_out;

    float4* c = (float4*)d_ws;  // OUT_DIM float4 = 128 KB scratch

    compute_c_kernel<<<OUT_DIM / 256, 256, 0, stream>>>(weight, c);
    gate_main_kernel<<<BATCH / ROWS, T, 0, stream>>>(
        x, c, (const int4*)idx_a, (const int4*)idx_b, (float4*)out);
}

// Round 6
// 443.109 us; speedup vs baseline: 1.0073x; 1.0073x over previous
//
#include <hip/hip_runtime.h>
#include <math.h>

#define IN_DIM  8192
#define OUT_DIM 8192
#define BATCH   8192
#define ROWS    16     // batch rows per block
#define T       1024   // threads per block

// Direct global->LDS DMA, 16B per lane. LDS dest is wave-uniform base
// (HW writes lane i at base + i*16); global src is per-lane.
#define GLOAD_LDS16(g, l) __builtin_amdgcn_global_load_lds( \
    (const __attribute__((address_space(1))) void*)(g),     \
    (__attribute__((address_space(3))) void*)(l), 16, 0, 0)

// GATE_COEFFS columns (g0,g1,g2,g3) per row i
__device__ __constant__ float GC0[16] = {0,0,0,0, 0,0,0,0, 1,1,1,1, 1,1,1,1};
__device__ __constant__ float GC1[16] = {0,0,1,1, 0,0,1,1, -1,-1,0,0, -1,-1,0,0};
__device__ __constant__ float GC2[16] = {0,0,0,0, 1,1,1,1, -1,-1,-1,-1, 0,0,0,0};
__device__ __constant__ float GC3[16] = {0,1,-1,0, -1,0,-2,-1, 1,2,0,1, 0,1,-1,0};

// Kernel 1: c[j] = softmax(weight[j,:]) @ GATE_COEFFS  -> float4 per column
__global__ __launch_bounds__(256) void compute_c_kernel(
    const float* __restrict__ weight, float4* __restrict__ c)
{
    int row = blockIdx.x * 256 + threadIdx.x;
    if (row >= OUT_DIM) return;
    const float* wr = weight + (size_t)row * 16;
    float v[16];
    float m = -1e30f;
#pragma unroll
    for (int i = 0; i < 16; ++i) { v[i] = wr[i]; m = fmaxf(m, v[i]); }
    float s = 0.f;
#pragma unroll
    for (int i = 0; i < 16; ++i) { v[i] = __expf(v[i] - m); s += v[i]; }
    float inv = 1.0f / s;
    float c0 = 0.f, c1 = 0.f, c2 = 0.f, c3 = 0.f;
#pragma unroll
    for (int i = 0; i < 16; ++i) {
        c0 = fmaf(v[i], GC0[i], c0);
        c1 = fmaf(v[i], GC1[i], c1);
        c2 = fmaf(v[i], GC2[i], c2);
        c3 = fmaf(v[i], GC3[i], c3);
    }
    c[row] = make_float4(c0 * inv, c1 * inv, c2 * inv, c3 * inv);
}

// Kernel 2: persistent block over 16 rows, TWO blocks per CU (the point of R6).
// - grid=512, LDS 64KB/block, __launch_bounds__(1024,8) => VGPR<=64 => 32 waves/CU
// - gather indices packed as u16 BYTE offsets (idx<<2), 8 persistent VGPRs
// - c register-resident (32 VGPRs); x row double-buffered via global_load_lds DMA
// - counted s_waitcnt vmcnt(2) + raw s_barrier per row (stores drain in background)
__global__ __launch_bounds__(T, 8) void gate_main_kernel(
    const float* __restrict__ x,
    const float4* __restrict__ c,
    const int4* __restrict__ ia4,
    const int4* __restrict__ ib4,
    float4* __restrict__ out)
{
    __shared__ float buf[2][IN_DIM];          // 64 KB
    const int tid  = threadIdx.x;
    const int wave = tid >> 6;
    const size_t r0 = (size_t)blockIdx.x * ROWS;

    // Persistent state: 8 packed-offset VGPRs + 32 coeff VGPRs.
    const int q0 = tid, q1 = tid + T;
    unsigned pkA0, pkA1, pkA2, pkA3, pkB0, pkB1, pkB2, pkB3;
    {
        int4 ia = ia4[q0], ib = ib4[q0];
        pkA0 = (unsigned)(ia.x << 2) | ((unsigned)(ib.x << 2) << 16);
        pkA1 = (unsigned)(ia.y << 2) | ((unsigned)(ib.y << 2) << 16);
        pkA2 = (unsigned)(ia.z << 2) | ((unsigned)(ib.z << 2) << 16);
        pkA3 = (unsigned)(ia.w << 2) | ((unsigned)(ib.w << 2) << 16);
        ia = ia4[q1]; ib = ib4[q1];
        pkB0 = (unsigned)(ia.x << 2) | ((unsigned)(ib.x << 2) << 16);
        pkB1 = (unsigned)(ia.y << 2) | ((unsigned)(ib.y << 2) << 16);
        pkB2 = (unsigned)(ia.z << 2) | ((unsigned)(ib.z << 2) << 16);
        pkB3 = (unsigned)(ia.w << 2) | ((unsigned)(ib.w << 2) << 16);
    }
    const float4 cA0 = c[4*q0+0], cA1 = c[4*q0+1], cA2 = c[4*q0+2], cA3 = c[4*q0+3];
    const float4 cB0 = c[4*q1+0], cB1 = c[4*q1+1], cB2 = c[4*q1+2], cB3 = c[4*q1+3];

    // Prologue: stage row 0 into buf[0].
    {
        const float* src = x + r0 * IN_DIM;
        GLOAD_LDS16(src + (tid << 2),        &buf[0][wave << 8]);
        GLOAD_LDS16(src + 4096 + (tid << 2), &buf[0][4096 + (wave << 8)]);
    }
    asm volatile("s_waitcnt vmcnt(0)" ::: "memory");
    __builtin_amdgcn_s_barrier();

    for (int r = 0; r < ROWS; ++r) {
        const int cur = r & 1;

        // (1) issue next-row DMA into the other buffer.
        if (r + 1 < ROWS) {
            const float* src = x + (r0 + r + 1) * IN_DIM;
            float* bn = buf[cur ^ 1];
            GLOAD_LDS16(src + (tid << 2),        bn + (wave << 8));
            GLOAD_LDS16(src + 4096 + (tid << 2), bn + 4096 + (wave << 8));
        }
        asm volatile("" ::: "memory");   // pin DMA issue before the stores below

        // (2) gather + compute + store current row
        const char* xb = (const char*)buf[cur];
        float4* orow = out + (r0 + r) * (OUT_DIM / 4);
        {
            float a0 = *(const float*)(xb + (pkA0 & 0xffffu));
            float b0 = *(const float*)(xb + (pkA0 >> 16));
            float a1 = *(const float*)(xb + (pkA1 & 0xffffu));
            float b1 = *(const float*)(xb + (pkA1 >> 16));
            float a2 = *(const float*)(xb + (pkA2 & 0xffffu));
            float b2 = *(const float*)(xb + (pkA2 >> 16));
            float a3 = *(const float*)(xb + (pkA3 & 0xffffu));
            float b3 = *(const float*)(xb + (pkA3 >> 16));
            float4 o;
            o.x = fmaf(a0, fmaf(b0, cA0.w, cA0.y), fmaf(b0, cA0.z, cA0.x));
            o.y = fmaf(a1, fmaf(b1, cA1.w, cA1.y), fmaf(b1, cA1.z, cA1.x));
            o.z = fmaf(a2, fmaf(b2, cA2.w, cA2.y), fmaf(b2, cA2.z, cA2.x));
            o.w = fmaf(a3, fmaf(b3, cA3.w, cA3.y), fmaf(b3, cA3.z, cA3.x));
            orow[q0] = o;
        }
        {
            float a0 = *(const float*)(xb + (pkB0 & 0xffffu));
            float b0 = *(const float*)(xb + (pkB0 >> 16));
            float a1 = *(const float*)(xb + (pkB1 & 0xffffu));
            float b1 = *(const float*)(xb + (pkB1 >> 16));
            float a2 = *(const float*)(xb + (pkB2 & 0xffffu));
            float b2 = *(const float*)(xb + (pkB2 >> 16));
            float a3 = *(const float*)(xb + (pkB3 & 0xffffu));
            float b3 = *(const float*)(xb + (pkB3 >> 16));
            float4 o;
            o.x = fmaf(a0, fmaf(b0, cB0.w, cB0.y), fmaf(b0, cB0.z, cB0.x));
            o.y = fmaf(a1, fmaf(b1, cB1.w, cB1.y), fmaf(b1, cB1.z, cB1.x));
            o.z = fmaf(a2, fmaf(b2, cB2.w, cB2.y), fmaf(b2, cB2.z, cB2.x));
            o.w = fmaf(a3, fmaf(b3, cB3.w, cB3.y), fmaf(b3, cB3.z, cB3.x));
            orow[q1] = o;
        }

        // (3) counted wait: leaves our 2 output stores in flight; guarantees
        // this row's 2 staging DMAs have landed in LDS.
        if (r + 1 < ROWS) {
            asm volatile("s_waitcnt vmcnt(2)" ::: "memory");
            __builtin_amdgcn_s_barrier();
        }
    }
}

extern "C" void kernel_launch(void* const* d_in, const int* in_sizes, int n_in,
                              void* d_out, int out_size, void* d_ws, size_t ws_size,
                              hipStream_t stream) {
    const float* x      = (const float*)d_in[0];
    const float* weight = (const float*)d_in[1];
    const int*   idx_a  = (const int*)d_in[2];
    const int*   idx_b  = (const int*)d_in[3];
    float* out = (float*)d_out;

    float4* c = (float4*)d_ws;  // OUT_DIM float4 = 128 KB scratch

    compute_c_kernel<<<OUT_DIM / 256, 256, 0, stream>>>(weight, c);
    gate_main_kernel<<<BATCH / ROWS, T, 0, stream>>>(
        x, c, (const int4*)idx_a, (const int4*)idx_b, (float4*)out);
}